// Round 11
// baseline (176.531 us; speedup 1.0000x reference)
//
#include <hip/hip_runtime.h>

// EuclideanFastAttention — MI355X (gfx950)
// A = (1/6) qr·kr^T per batch (256x256, K=6912, split by grid dir g=6),
// out = A·v.  R11 = R10 + hardware packed bf16 converts (v_cvt_pk_bf16_f32)
// in qkv staging/epilogues and gemm2 A-pack.

typedef unsigned short u16;
typedef __attribute__((ext_vector_type(8))) short short8;   // 8 x bf16 bits (MFMA frag)
typedef __attribute__((ext_vector_type(4))) float f32x4;    // MFMA acc

static constexpr int N_NODES = 4096;
static constexpr int NBATCH  = 16;
static constexpr int NB      = 256;
static constexpr int NDEG    = 9;
static constexpr int MD      = NDEG * 128;    // 1152
static constexpr int KTOT    = 6 * MD;        // 6912
static constexpr size_t ASLICE = (size_t)NBATCH * NB * NB;   // elems per g-slice of Apart

// ws layout (bytes), aliased along the kernel timeline
static constexpr size_t OFF_WT  = 0;                                  // 9*16384 bf16
static constexpr size_t OFF_QR  = OFF_WT  + (size_t)9*16384*2;        // [g][n][1152] 56.6MB
static constexpr size_t OFF_KR  = OFF_QR  + (size_t)N_NODES*KTOT*2;   // 56.6MB
static constexpr size_t OFF_VT  = OFF_KR  + (size_t)N_NODES*KTOT*2;   // [d][n] 9.4MB
static constexpr size_t OFF_AP  = OFF_VT  + (size_t)N_NODES*MD*2;     // 6*16*65536*2 = 12.6MB
// high-water = OFF_AP + 12.6MB = 135.6MB (proven in R6/R8/R10)

__device__ inline u16 f2bf(float x) {
    union { float f; unsigned u; } v; v.f = x;
    unsigned r = v.u + 0x7fffu + ((v.u >> 16) & 1u);   // RNE
    return (u16)(r >> 16);
}
__device__ inline float bf2f(u16 h) {
    union { unsigned u; float f; } v; v.u = ((unsigned)h) << 16; return v.f;
}
// packed f32x2 -> bf16x2 (low = a).  HW RNE on gfx950 (1 VALU op vs ~8).
__device__ inline unsigned pk2bf(float a, float b) {
#if __has_builtin(__builtin_amdgcn_cvt_pk_bf16_f32)
    typedef __attribute__((ext_vector_type(2))) __bf16 bf2_t;
    union { bf2_t v; unsigned u; } cv;
    cv.v = __builtin_amdgcn_cvt_pk_bf16_f32(a, b);
    return cv.u;
#else
    return (unsigned)f2bf(a) | ((unsigned)f2bf(b) << 16);
#endif
}

// ---------------- kernel 1: W transpose + bf16 cast --------------------------
// wt[(mat*3+l)][j][f] = W[l][f][j];  grid 36 = 9 blk x 4 tiles
__global__ __launch_bounds__(256) void k_prep(const float* __restrict__ Wq,
                                              const float* __restrict__ Wk,
                                              const float* __restrict__ Wv,
                                              u16* __restrict__ wt) {
    int t = blockIdx.x, tid = threadIdx.x;
    int blk = t >> 2, tt = t & 3;
    int mat = blk / 3, l = blk % 3;
    const float* W = (mat == 0 ? Wq : (mat == 1 ? Wk : Wv)) + (size_t)l * 16384;
    int j0 = (tt >> 1) * 64, f0 = (tt & 1) * 64;
    __shared__ u16 tile[64 * 72];
    for (int e = tid; e < 1024; e += 256) {
        int r = e >> 4, c = e & 15;
        float4 wv = *(const float4*)(W + (size_t)(f0 + r) * 128 + j0 + c * 4);
        tile[(c * 4 + 0) * 72 + r] = f2bf(wv.x);
        tile[(c * 4 + 1) * 72 + r] = f2bf(wv.y);
        tile[(c * 4 + 2) * 72 + r] = f2bf(wv.z);
        tile[(c * 4 + 3) * 72 + r] = f2bf(wv.w);
    }
    __syncthreads();
    u16* dst = wt + (size_t)blk * 16384;
    for (int e = tid; e < 512; e += 256) {
        int j = e >> 3, c = e & 7;
        *(uint4*)(dst + (size_t)(j0 + j) * 128 + f0 + c * 8) = *(const uint4*)(tile + j * 72 + c * 8);
    }
}

// ---------------- kernel 2: dense(q/k/v) + bias + RoPE (inline trig) ---------
// grid (64 node-tiles, 9 m, 3 mats).  mat 2 writes vt[d][n] directly.
// qr/kr layout: [g][node][m*128+j]  (g-major for gemm1 streaming)
__global__ __launch_bounds__(256) void k_qkv(const float* __restrict__ X,
                                             const u16* __restrict__ wt,
                                             const float* __restrict__ bq,
                                             const float* __restrict__ bk,
                                             const float* __restrict__ bv,
                                             const float* __restrict__ pos,
                                             u16* __restrict__ qr,
                                             u16* __restrict__ kr,
                                             u16* __restrict__ vt) {
    const int nt = blockIdx.x, m = blockIdx.y, mat = blockIdx.z;
    const int n0 = nt * 64;
    const int deg = (m == 0) ? 0 : (m < 4 ? 1 : 2);
    const int tid = threadIdx.x;

    __shared__ u16 smem[26112];       // Xs(64x136) ++ Ws(128x136); reused as O0/O1/T
    __shared__ float posS[192];       // pos[n0..n0+63][3]
    u16* Xs = smem;
    u16* Ws = smem + 64 * 136;

    if (tid < 192) posS[tid] = pos[(size_t)n0 * 3 + tid];

    for (int e = tid; e < 2048; e += 256) {            // stage X (fp32->bf16, HW pk)
        int r = e >> 5, f4 = e & 31;
        float4 xv = *(const float4*)(X + (size_t)(n0 + r) * MD + m * 128 + f4 * 4);
        uint2 o = make_uint2(pk2bf(xv.x, xv.y), pk2bf(xv.z, xv.w));
        *(uint2*)(Xs + r * 136 + f4 * 4) = o;
    }
    {
        const uint4* wsrc = (const uint4*)(wt + (size_t)(mat * 3 + deg) * 16384);
        for (int e = tid; e < 2048; e += 256) {
            int j = e >> 4, f8 = e & 15;
            *(uint4*)(Ws + j * 136 + f8 * 8) = wsrc[j * 16 + f8];
        }
    }
    __syncthreads();

    const int w = tid >> 6, lane = tid & 63, quad = lane >> 4, lrow = lane & 15;
    f32x4 acc[8];
#pragma unroll
    for (int ct = 0; ct < 8; ct++) acc[ct] = (f32x4){0.f, 0.f, 0.f, 0.f};
#pragma unroll
    for (int ks = 0; ks < 4; ks++) {
        short8 a = *(const short8*)(Xs + (w * 16 + lrow) * 136 + ks * 32 + quad * 8);
#pragma unroll
        for (int ct = 0; ct < 8; ct++) {
            short8 bfr = *(const short8*)(Ws + (ct * 16 + lrow) * 136 + ks * 32 + quad * 8);
            acc[ct] = __builtin_amdgcn_mfma_f32_16x16x32_bf16(a, bfr, acc[ct], 0, 0, 0);
        }
    }

    const float* bias = (mat == 0) ? bq : ((mat == 1) ? bk : bv);
    float yv[8][4];
#pragma unroll
    for (int ct = 0; ct < 8; ct++) {
        float bj = (m == 0) ? bias[ct * 16 + lrow] : 0.0f;
#pragma unroll
        for (int r = 0; r < 4; r++) yv[ct][r] = acc[ct][r] + bj;
    }

    if (mat == 2) {                    // v: reg->LDS transpose T[j][nl], packed stores
        u16* T = Ws;                   // 128 x 66
        const int nlb = w * 16 + quad * 4;   // 4 consecutive nl per lane
        __syncthreads();
#pragma unroll
        for (int ct = 0; ct < 8; ct++) {
            int j = ct * 16 + lrow;
            *(unsigned*)(T + j * 66 + nlb)     = pk2bf(yv[ct][0], yv[ct][1]);
            *(unsigned*)(T + j * 66 + nlb + 2) = pk2bf(yv[ct][2], yv[ct][3]);
        }
        __syncthreads();
        for (int e = tid; e < 1024; e += 256) {
            int d = e >> 3, c = e & 7;
            *(uint4*)(vt + (size_t)(m * 128 + d) * N_NODES + n0 + c * 8) =
                *(const uint4*)(T + d * 66 + c * 8);
        }
        return;
    }

    float pv[8][4];                    // partner feature j^1 (same C row)
#pragma unroll
    for (int ct = 0; ct < 8; ct++)
#pragma unroll
        for (int r = 0; r < 4; r++) pv[ct][r] = __shfl_xor(yv[ct][r], 1);

    float pr[4][3];
#pragma unroll
    for (int r = 0; r < 4; r++) {
        int nl = w * 16 + quad * 4 + r;
#pragma unroll
        for (int gp = 0; gp < 3; gp++) pr[r][gp] = posS[nl * 3 + gp];
    }
    const float thq = (float)(lrow >> 1) * (8.0f / 630.0f);
    const float th8 = 8.0f * (8.0f / 630.0f);

    u16* O0 = Xs;                      // Xs dead after MFMA
    u16* O1 = Ws;
    u16* dst = (mat == 0) ? qr : kr;
    const bool even = !(lrow & 1);

    for (int gp = 0; gp < 3; gp++) {
        __syncthreads();
#pragma unroll
        for (int ct = 0; ct < 8; ct++) {
            float th = thq + (float)ct * th8;          // theta_i, i = ct*8 + (lrow>>1)
#pragma unroll
            for (int r = 0; r < 4; r++) {
                int nl = w * 16 + quad * 4 + r;
                float s, c;
                __sincosf(pr[r][gp] * th, &s, &c);
                float t1 = yv[ct][r] * c, t2 = pv[ct][r] * s;
                float r0 = even ? (t1 - t2) : (t1 + t2);
                float r1 = even ? (t1 + t2) : (t1 - t2);
                float r0n = __shfl_xor(r0, 1);         // partner col's result
                float r1n = __shfl_xor(r1, 1);
                if (even) {                            // packed u32 store (cols j, j+1)
                    *(unsigned*)(O0 + nl * 136 + ct * 16 + lrow) = pk2bf(r0, r0n);
                    *(unsigned*)(O1 + nl * 136 + ct * 16 + lrow) = pk2bf(r1, r1n);
                }
            }
        }
        __syncthreads();
        for (int e = tid; e < 1024; e += 256) {
            int nl = e >> 4, c = e & 15;
            size_t o0 = ((size_t)(gp * 2) * N_NODES + n0 + nl) * MD + m * 128 + c * 8;
            *(uint4*)(dst + o0)                      = *(const uint4*)(O0 + nl * 136 + c * 8);
            *(uint4*)(dst + o0 + (size_t)N_NODES*MD) = *(const uint4*)(O1 + nl * 136 + c * 8);
        }
    }
}

// ---------------- kernel 3: Apart[g] = qr_g · kr_g^T  (1-D XCD decode) -------
// 1536 blocks 1-D.  Under rr-8 XCD assignment, XCD c gets, per 64-block group
// (= 4 (b,g) pairs): one bg (c&3) and 8 tiles (2 q-strips x 4 k-strips)
// -> q 4x / k 2x reuse inside its L2.  [R9/R10: gemm1 out of top-5]
__global__ __launch_bounds__(256) void k_gemm1(const u16* __restrict__ qr,
                                               const u16* __restrict__ kr,
                                               u16* __restrict__ Apart) {
    int idx = blockIdx.x;              // 0..1535
    int grp = idx >> 6;                // 0..23
    int sub = idx & 63;
    int c   = sub & 7;                 // XCD id under round-robin-8
    int j   = sub >> 3;                // 0..7
    int bg  = grp * 4 + (c & 3);       // 0..95
    int g   = bg >> 4, b = bg & 15;
    int tr  = (c >> 2) * 2 + (j & 1);  // 0..3
    int tc  = j >> 1;                  // 0..3

    int qn0 = b * NB + tr * 64, kn0 = b * NB + tc * 64;
    const size_t gbase = (size_t)g * N_NODES;
    int tid = threadIdx.x;
    __shared__ u16 Qs[64 * 72];
    __shared__ u16 Ks[64 * 72];
    int w = tid >> 6, lane = tid & 63, quad = lane >> 4, lrow = lane & 15;

    f32x4 acc[4];
#pragma unroll
    for (int ct = 0; ct < 4; ct++) acc[ct] = (f32x4){0.f, 0.f, 0.f, 0.f};

    for (int kc = 0; kc < MD / 64; kc++) {     // 18
        int k0 = kc * 64;
#pragma unroll
        for (int e = tid; e < 512; e += 256) {
            int r = e >> 3, s = e & 7;
            *(uint4*)(Qs + r * 72 + s * 8) = *(const uint4*)(qr + (gbase + qn0 + r) * MD + k0 + s * 8);
            *(uint4*)(Ks + r * 72 + s * 8) = *(const uint4*)(kr + (gbase + kn0 + r) * MD + k0 + s * 8);
        }
        __syncthreads();
#pragma unroll
        for (int ks = 0; ks < 2; ks++) {
            short8 a = *(const short8*)(Qs + (w * 16 + lrow) * 72 + ks * 32 + quad * 8);
#pragma unroll
            for (int ct = 0; ct < 4; ct++) {
                short8 bfr = *(const short8*)(Ks + (ct * 16 + lrow) * 72 + ks * 32 + quad * 8);
                acc[ct] = __builtin_amdgcn_mfma_f32_16x16x32_bf16(a, bfr, acc[ct], 0, 0, 0);
            }
        }
        __syncthreads();
    }
    u16* dst = Apart + ((size_t)g * NBATCH + b) * (NB * NB);
#pragma unroll
    for (int ct = 0; ct < 4; ct++)
#pragma unroll
        for (int r = 0; r < 4; r++) {
            int rib = tr * 64 + w * 16 + quad * 4 + r;
            int cib = tc * 64 + ct * 16 + lrow;
            dst[(size_t)rib * NB + cib] = f2bf(acc[ct][r]);
        }
}

// ---------------- kernel 4: out = (1/6 sum_g Apart[g]) · v  (+mask) ----------
// grid (4 rt, 9 dcb, 16 b).  A-staging folds the 6-slice reduction (f32 accum).
__global__ __launch_bounds__(256) void k_gemm2(const u16* __restrict__ Ap,
                                               const u16* __restrict__ vt,
                                               const int* __restrict__ gmask,
                                               float* __restrict__ out) {
    int rt = blockIdx.x, dcb = blockIdx.y, b = blockIdx.z;
    int d0 = dcb * 128;
    int tid = threadIdx.x;
    __shared__ u16 As[64 * 72];
    __shared__ u16 Vs[128 * 72];
    int w = tid >> 6, lane = tid & 63, quad = lane >> 4, lrow = lane & 15;

    f32x4 acc[8];
#pragma unroll
    for (int ct = 0; ct < 8; ct++) acc[ct] = (f32x4){0.f, 0.f, 0.f, 0.f};

    const float sc6 = 1.0f / 6.0f;
    for (int kc = 0; kc < 4; kc++) {
        int k0 = kc * 64;
#pragma unroll
        for (int e = tid; e < 512; e += 256) {     // A: sum 6 slices, scale, pack (HW pk)
            int r = e >> 3, c8 = e & 7;
            size_t off = (size_t)b * (NB * NB) + (size_t)(rt * 64 + r) * NB + k0 + c8 * 8;
            float sacc[8];
#pragma unroll
            for (int i = 0; i < 8; i++) sacc[i] = 0.f;
#pragma unroll
            for (int s = 0; s < 6; s++) {
                uint4 v = *(const uint4*)(Ap + (size_t)s * ASLICE + off);
                const unsigned* u = (const unsigned*)&v;
#pragma unroll
                for (int h = 0; h < 4; h++) {
                    sacc[h * 2]     += bf2f((u16)(u[h] & 0xffff));
                    sacc[h * 2 + 1] += bf2f((u16)(u[h] >> 16));
                }
            }
            unsigned o32[4];
#pragma unroll
            for (int i = 0; i < 4; i++) o32[i] = pk2bf(sacc[i * 2] * sc6, sacc[i * 2 + 1] * sc6);
            *(uint4*)(As + r * 72 + c8 * 8) = *(const uint4*)o32;
        }
#pragma unroll
        for (int e = tid; e < 1024; e += 256) {
            int rr = e >> 3, sc2 = e & 7;
            *(uint4*)(Vs + rr * 72 + sc2 * 8) =
                *(const uint4*)(vt + (size_t)(d0 + rr) * N_NODES + b * NB + k0 + sc2 * 8);
        }
        __syncthreads();
#pragma unroll
        for (int ks = 0; ks < 2; ks++) {
            short8 a = *(const short8*)(As + (w * 16 + lrow) * 72 + ks * 32 + quad * 8);
#pragma unroll
            for (int ct = 0; ct < 8; ct++) {
                short8 bfr = *(const short8*)(Vs + (ct * 16 + lrow) * 72 + ks * 32 + quad * 8);
                acc[ct] = __builtin_amdgcn_mfma_f32_16x16x32_bf16(a, bfr, acc[ct], 0, 0, 0);
            }
        }
        __syncthreads();
    }
    int mv = gmask[b];
#pragma unroll
    for (int ct = 0; ct < 8; ct++)
#pragma unroll
        for (int r = 0; r < 4; r++) {
            int node = b * NB + rt * 64 + w * 16 + quad * 4 + r;
            int d = d0 + ct * 16 + lrow;
            out[(size_t)node * MD + d] = mv ? acc[ct][r] : 0.0f;
        }
}

// ---------------- launch -----------------------------------------------------
extern "C" void kernel_launch(void* const* d_in, const int* in_sizes, int n_in,
                              void* d_out, int out_size, void* d_ws, size_t ws_size,
                              hipStream_t stream) {
    (void)in_sizes; (void)n_in; (void)out_size; (void)ws_size;

    const float* X    = (const float*)d_in[0];
    const float* pos  = (const float*)d_in[1];
    const int*   gmask= (const int*)  d_in[3];
    const float* Wq   = (const float*)d_in[4];
    const float* bq   = (const float*)d_in[5];
    const float* Wk   = (const float*)d_in[6];
    const float* bk   = (const float*)d_in[7];
    const float* Wv   = (const float*)d_in[8];
    const float* bv   = (const float*)d_in[9];
    float* out = (float*)d_out;

    char* ws = (char*)d_ws;
    u16*   wt   = (u16*)  (ws + OFF_WT);
    u16*   qrp  = (u16*)  (ws + OFF_QR);
    u16*   krp  = (u16*)  (ws + OFF_KR);
    u16*   vtp  = (u16*)  (ws + OFF_VT);
    u16*   App  = (u16*)  (ws + OFF_AP);

    k_prep <<<dim3(36),         dim3(256), 0, stream>>>(Wq, Wk, Wv, wt);
    k_qkv  <<<dim3(64, 9, 3),   dim3(256), 0, stream>>>(X, wt, bq, bk, bv, pos, qrp, krp, vtp);
    k_gemm1<<<dim3(1536),       dim3(256), 0, stream>>>(qrp, krp, App);
    k_gemm2<<<dim3(4, 9, 16),   dim3(256), 0, stream>>>(App, vtp, gmask, out);
}

// Round 12
// 171.046 us; speedup vs baseline: 1.0321x; 1.0321x over previous
//
#include <hip/hip_runtime.h>

// EuclideanFastAttention — MI355X (gfx950)
// A = (1/6) qr·kr^T per batch (256x256, K=6912, split by grid dir g=6),
// out = A·v.  R12 = R10 + pk2bf ONLY in shuffle-free spots (X-stage, v-branch,
// gemm2 A-pack).  RoPE epilogue byte-identical to R10 (R11's shfl version lost).

typedef unsigned short u16;
typedef __attribute__((ext_vector_type(8))) short short8;   // 8 x bf16 bits (MFMA frag)
typedef __attribute__((ext_vector_type(4))) float f32x4;    // MFMA acc

static constexpr int N_NODES = 4096;
static constexpr int NBATCH  = 16;
static constexpr int NB      = 256;
static constexpr int NDEG    = 9;
static constexpr int MD      = NDEG * 128;    // 1152
static constexpr int KTOT    = 6 * MD;        // 6912
static constexpr size_t ASLICE = (size_t)NBATCH * NB * NB;   // elems per g-slice of Apart

// ws layout (bytes), aliased along the kernel timeline
static constexpr size_t OFF_WT  = 0;                                  // 9*16384 bf16
static constexpr size_t OFF_QR  = OFF_WT  + (size_t)9*16384*2;        // [g][n][1152] 56.6MB
static constexpr size_t OFF_KR  = OFF_QR  + (size_t)N_NODES*KTOT*2;   // 56.6MB
static constexpr size_t OFF_VT  = OFF_KR  + (size_t)N_NODES*KTOT*2;   // [d][n] 9.4MB
static constexpr size_t OFF_AP  = OFF_VT  + (size_t)N_NODES*MD*2;     // 6*16*65536*2 = 12.6MB
// high-water = OFF_AP + 12.6MB = 135.6MB (proven in R6/R8/R10)

__device__ inline u16 f2bf(float x) {
    union { float f; unsigned u; } v; v.f = x;
    unsigned r = v.u + 0x7fffu + ((v.u >> 16) & 1u);   // RNE
    return (u16)(r >> 16);
}
__device__ inline float bf2f(u16 h) {
    union { unsigned u; float f; } v; v.u = ((unsigned)h) << 16; return v.f;
}
// packed f32x2 -> bf16x2 (low = a).  HW RNE on gfx950 (1 VALU op vs ~8).
__device__ inline unsigned pk2bf(float a, float b) {
#if __has_builtin(__builtin_amdgcn_cvt_pk_bf16_f32)
    typedef __attribute__((ext_vector_type(2))) __bf16 bf2_t;
    union { bf2_t v; unsigned u; } cv;
    cv.v = __builtin_amdgcn_cvt_pk_bf16_f32(a, b);
    return cv.u;
#else
    return (unsigned)f2bf(a) | ((unsigned)f2bf(b) << 16);
#endif
}

// ---------------- kernel 1: W transpose + bf16 cast --------------------------
// wt[(mat*3+l)][j][f] = W[l][f][j];  grid 36 = 9 blk x 4 tiles
__global__ __launch_bounds__(256) void k_prep(const float* __restrict__ Wq,
                                              const float* __restrict__ Wk,
                                              const float* __restrict__ Wv,
                                              u16* __restrict__ wt) {
    int t = blockIdx.x, tid = threadIdx.x;
    int blk = t >> 2, tt = t & 3;
    int mat = blk / 3, l = blk % 3;
    const float* W = (mat == 0 ? Wq : (mat == 1 ? Wk : Wv)) + (size_t)l * 16384;
    int j0 = (tt >> 1) * 64, f0 = (tt & 1) * 64;
    __shared__ u16 tile[64 * 72];
    for (int e = tid; e < 1024; e += 256) {
        int r = e >> 4, c = e & 15;
        float4 wv = *(const float4*)(W + (size_t)(f0 + r) * 128 + j0 + c * 4);
        tile[(c * 4 + 0) * 72 + r] = f2bf(wv.x);
        tile[(c * 4 + 1) * 72 + r] = f2bf(wv.y);
        tile[(c * 4 + 2) * 72 + r] = f2bf(wv.z);
        tile[(c * 4 + 3) * 72 + r] = f2bf(wv.w);
    }
    __syncthreads();
    u16* dst = wt + (size_t)blk * 16384;
    for (int e = tid; e < 512; e += 256) {
        int j = e >> 3, c = e & 7;
        *(uint4*)(dst + (size_t)(j0 + j) * 128 + f0 + c * 8) = *(const uint4*)(tile + j * 72 + c * 8);
    }
}

// ---------------- kernel 2: dense(q/k/v) + bias + RoPE (inline trig) ---------
// grid (64 node-tiles, 9 m, 3 mats).  mat 2 writes vt[d][n] directly.
// qr/kr layout: [g][node][m*128+j]  (g-major for gemm1 streaming)
__global__ __launch_bounds__(256) void k_qkv(const float* __restrict__ X,
                                             const u16* __restrict__ wt,
                                             const float* __restrict__ bq,
                                             const float* __restrict__ bk,
                                             const float* __restrict__ bv,
                                             const float* __restrict__ pos,
                                             u16* __restrict__ qr,
                                             u16* __restrict__ kr,
                                             u16* __restrict__ vt) {
    const int nt = blockIdx.x, m = blockIdx.y, mat = blockIdx.z;
    const int n0 = nt * 64;
    const int deg = (m == 0) ? 0 : (m < 4 ? 1 : 2);
    const int tid = threadIdx.x;

    __shared__ u16 smem[26112];       // Xs(64x136) ++ Ws(128x136); reused as O0/O1/T
    __shared__ float posS[192];       // pos[n0..n0+63][3]
    u16* Xs = smem;
    u16* Ws = smem + 64 * 136;

    if (tid < 192) posS[tid] = pos[(size_t)n0 * 3 + tid];

    for (int e = tid; e < 2048; e += 256) {            // stage X (fp32->bf16, HW pk)
        int r = e >> 5, f4 = e & 31;
        float4 xv = *(const float4*)(X + (size_t)(n0 + r) * MD + m * 128 + f4 * 4);
        uint2 o = make_uint2(pk2bf(xv.x, xv.y), pk2bf(xv.z, xv.w));
        *(uint2*)(Xs + r * 136 + f4 * 4) = o;
    }
    {
        const uint4* wsrc = (const uint4*)(wt + (size_t)(mat * 3 + deg) * 16384);
        for (int e = tid; e < 2048; e += 256) {
            int j = e >> 4, f8 = e & 15;
            *(uint4*)(Ws + j * 136 + f8 * 8) = wsrc[j * 16 + f8];
        }
    }
    __syncthreads();

    const int w = tid >> 6, lane = tid & 63, quad = lane >> 4, lrow = lane & 15;
    f32x4 acc[8];
#pragma unroll
    for (int ct = 0; ct < 8; ct++) acc[ct] = (f32x4){0.f, 0.f, 0.f, 0.f};
#pragma unroll
    for (int ks = 0; ks < 4; ks++) {
        short8 a = *(const short8*)(Xs + (w * 16 + lrow) * 136 + ks * 32 + quad * 8);
#pragma unroll
        for (int ct = 0; ct < 8; ct++) {
            short8 bfr = *(const short8*)(Ws + (ct * 16 + lrow) * 136 + ks * 32 + quad * 8);
            acc[ct] = __builtin_amdgcn_mfma_f32_16x16x32_bf16(a, bfr, acc[ct], 0, 0, 0);
        }
    }

    const float* bias = (mat == 0) ? bq : ((mat == 1) ? bk : bv);
    float yv[8][4];
#pragma unroll
    for (int ct = 0; ct < 8; ct++) {
        float bj = (m == 0) ? bias[ct * 16 + lrow] : 0.0f;
#pragma unroll
        for (int r = 0; r < 4; r++) yv[ct][r] = acc[ct][r] + bj;
    }

    if (mat == 2) {                    // v: reg->LDS transpose T[j][nl], packed stores
        u16* T = Ws;                   // 128 x 66
        const int nlb = w * 16 + quad * 4;   // 4 consecutive nl per lane
        __syncthreads();
#pragma unroll
        for (int ct = 0; ct < 8; ct++) {
            int j = ct * 16 + lrow;
            *(unsigned*)(T + j * 66 + nlb)     = pk2bf(yv[ct][0], yv[ct][1]);
            *(unsigned*)(T + j * 66 + nlb + 2) = pk2bf(yv[ct][2], yv[ct][3]);
        }
        __syncthreads();
        for (int e = tid; e < 1024; e += 256) {
            int d = e >> 3, c = e & 7;
            *(uint4*)(vt + (size_t)(m * 128 + d) * N_NODES + n0 + c * 8) =
                *(const uint4*)(T + d * 66 + c * 8);
        }
        return;
    }

    float pv[8][4];                    // partner feature j^1 (same C row)
#pragma unroll
    for (int ct = 0; ct < 8; ct++)
#pragma unroll
        for (int r = 0; r < 4; r++) pv[ct][r] = __shfl_xor(yv[ct][r], 1);

    float pr[4][3];
#pragma unroll
    for (int r = 0; r < 4; r++) {
        int nl = w * 16 + quad * 4 + r;
#pragma unroll
        for (int gp = 0; gp < 3; gp++) pr[r][gp] = posS[nl * 3 + gp];
    }
    const float thq = (float)(lrow >> 1) * (8.0f / 630.0f);
    const float th8 = 8.0f * (8.0f / 630.0f);

    u16* O0 = Xs;                      // Xs dead after MFMA
    u16* O1 = Ws;
    u16* dst = (mat == 0) ? qr : kr;
    const bool even = !(lrow & 1);

    for (int gp = 0; gp < 3; gp++) {   // R10-proven scalar epilogue
        __syncthreads();
#pragma unroll
        for (int ct = 0; ct < 8; ct++) {
            float th = thq + (float)ct * th8;          // theta_i, i = ct*8 + (lrow>>1)
#pragma unroll
            for (int r = 0; r < 4; r++) {
                int nl = w * 16 + quad * 4 + r;
                float s, c;
                __sincosf(pr[r][gp] * th, &s, &c);
                float t1 = yv[ct][r] * c, t2 = pv[ct][r] * s;
                float r0, r1;
                if (even) { r0 = t1 - t2; r1 = t1 + t2; }
                else      { r0 = t1 + t2; r1 = t1 - t2; }
                O0[nl * 136 + ct * 16 + lrow] = f2bf(r0);
                O1[nl * 136 + ct * 16 + lrow] = f2bf(r1);
            }
        }
        __syncthreads();
        for (int e = tid; e < 1024; e += 256) {
            int nl = e >> 4, c = e & 15;
            size_t o0 = ((size_t)(gp * 2) * N_NODES + n0 + nl) * MD + m * 128 + c * 8;
            *(uint4*)(dst + o0)                      = *(const uint4*)(O0 + nl * 136 + c * 8);
            *(uint4*)(dst + o0 + (size_t)N_NODES*MD) = *(const uint4*)(O1 + nl * 136 + c * 8);
        }
    }
}

// ---------------- kernel 3: Apart[g] = qr_g · kr_g^T  (1-D XCD decode) -------
// 1536 blocks 1-D.  Under rr-8 XCD assignment, XCD c gets, per 64-block group
// (= 4 (b,g) pairs): one bg (c&3) and 8 tiles (2 q-strips x 4 k-strips)
// -> q 4x / k 2x reuse inside its L2.  [R9/R10: gemm1 out of top-5]
__global__ __launch_bounds__(256) void k_gemm1(const u16* __restrict__ qr,
                                               const u16* __restrict__ kr,
                                               u16* __restrict__ Apart) {
    int idx = blockIdx.x;              // 0..1535
    int grp = idx >> 6;                // 0..23
    int sub = idx & 63;
    int c   = sub & 7;                 // XCD id under round-robin-8
    int j   = sub >> 3;                // 0..7
    int bg  = grp * 4 + (c & 3);       // 0..95
    int g   = bg >> 4, b = bg & 15;
    int tr  = (c >> 2) * 2 + (j & 1);  // 0..3
    int tc  = j >> 1;                  // 0..3

    int qn0 = b * NB + tr * 64, kn0 = b * NB + tc * 64;
    const size_t gbase = (size_t)g * N_NODES;
    int tid = threadIdx.x;
    __shared__ u16 Qs[64 * 72];
    __shared__ u16 Ks[64 * 72];
    int w = tid >> 6, lane = tid & 63, quad = lane >> 4, lrow = lane & 15;

    f32x4 acc[4];
#pragma unroll
    for (int ct = 0; ct < 4; ct++) acc[ct] = (f32x4){0.f, 0.f, 0.f, 0.f};

    for (int kc = 0; kc < MD / 64; kc++) {     // 18
        int k0 = kc * 64;
#pragma unroll
        for (int e = tid; e < 512; e += 256) {
            int r = e >> 3, s = e & 7;
            *(uint4*)(Qs + r * 72 + s * 8) = *(const uint4*)(qr + (gbase + qn0 + r) * MD + k0 + s * 8);
            *(uint4*)(Ks + r * 72 + s * 8) = *(const uint4*)(kr + (gbase + kn0 + r) * MD + k0 + s * 8);
        }
        __syncthreads();
#pragma unroll
        for (int ks = 0; ks < 2; ks++) {
            short8 a = *(const short8*)(Qs + (w * 16 + lrow) * 72 + ks * 32 + quad * 8);
#pragma unroll
            for (int ct = 0; ct < 4; ct++) {
                short8 bfr = *(const short8*)(Ks + (ct * 16 + lrow) * 72 + ks * 32 + quad * 8);
                acc[ct] = __builtin_amdgcn_mfma_f32_16x16x32_bf16(a, bfr, acc[ct], 0, 0, 0);
            }
        }
        __syncthreads();
    }
    u16* dst = Apart + ((size_t)g * NBATCH + b) * (NB * NB);
#pragma unroll
    for (int ct = 0; ct < 4; ct++)
#pragma unroll
        for (int r = 0; r < 4; r++) {
            int rib = tr * 64 + w * 16 + quad * 4 + r;
            int cib = tc * 64 + ct * 16 + lrow;
            dst[(size_t)rib * NB + cib] = f2bf(acc[ct][r]);
        }
}

// ---------------- kernel 4: out = (1/6 sum_g Apart[g]) · v  (+mask) ----------
// grid (4 rt, 9 dcb, 16 b).  A-staging folds the 6-slice reduction (f32 accum).
__global__ __launch_bounds__(256) void k_gemm2(const u16* __restrict__ Ap,
                                               const u16* __restrict__ vt,
                                               const int* __restrict__ gmask,
                                               float* __restrict__ out) {
    int rt = blockIdx.x, dcb = blockIdx.y, b = blockIdx.z;
    int d0 = dcb * 128;
    int tid = threadIdx.x;
    __shared__ u16 As[64 * 72];
    __shared__ u16 Vs[128 * 72];
    int w = tid >> 6, lane = tid & 63, quad = lane >> 4, lrow = lane & 15;

    f32x4 acc[8];
#pragma unroll
    for (int ct = 0; ct < 8; ct++) acc[ct] = (f32x4){0.f, 0.f, 0.f, 0.f};

    const float sc6 = 1.0f / 6.0f;
    for (int kc = 0; kc < 4; kc++) {
        int k0 = kc * 64;
#pragma unroll
        for (int e = tid; e < 512; e += 256) {     // A: sum 6 slices, scale, pack (HW pk)
            int r = e >> 3, c8 = e & 7;
            size_t off = (size_t)b * (NB * NB) + (size_t)(rt * 64 + r) * NB + k0 + c8 * 8;
            float sacc[8];
#pragma unroll
            for (int i = 0; i < 8; i++) sacc[i] = 0.f;
#pragma unroll
            for (int s = 0; s < 6; s++) {
                uint4 v = *(const uint4*)(Ap + (size_t)s * ASLICE + off);
                const unsigned* u = (const unsigned*)&v;
#pragma unroll
                for (int h = 0; h < 4; h++) {
                    sacc[h * 2]     += bf2f((u16)(u[h] & 0xffff));
                    sacc[h * 2 + 1] += bf2f((u16)(u[h] >> 16));
                }
            }
            unsigned o32[4];
#pragma unroll
            for (int i = 0; i < 4; i++) o32[i] = pk2bf(sacc[i * 2] * sc6, sacc[i * 2 + 1] * sc6);
            *(uint4*)(As + r * 72 + c8 * 8) = *(const uint4*)o32;
        }
#pragma unroll
        for (int e = tid; e < 1024; e += 256) {
            int rr = e >> 3, sc2 = e & 7;
            *(uint4*)(Vs + rr * 72 + sc2 * 8) =
                *(const uint4*)(vt + (size_t)(d0 + rr) * N_NODES + b * NB + k0 + sc2 * 8);
        }
        __syncthreads();
#pragma unroll
        for (int ks = 0; ks < 2; ks++) {
            short8 a = *(const short8*)(As + (w * 16 + lrow) * 72 + ks * 32 + quad * 8);
#pragma unroll
            for (int ct = 0; ct < 8; ct++) {
                short8 bfr = *(const short8*)(Vs + (ct * 16 + lrow) * 72 + ks * 32 + quad * 8);
                acc[ct] = __builtin_amdgcn_mfma_f32_16x16x32_bf16(a, bfr, acc[ct], 0, 0, 0);
            }
        }
        __syncthreads();
    }
    int mv = gmask[b];
#pragma unroll
    for (int ct = 0; ct < 8; ct++)
#pragma unroll
        for (int r = 0; r < 4; r++) {
            int node = b * NB + rt * 64 + w * 16 + quad * 4 + r;
            int d = d0 + ct * 16 + lrow;
            out[(size_t)node * MD + d] = mv ? acc[ct][r] : 0.0f;
        }
}

// ---------------- launch -----------------------------------------------------
extern "C" void kernel_launch(void* const* d_in, const int* in_sizes, int n_in,
                              void* d_out, int out_size, void* d_ws, size_t ws_size,
                              hipStream_t stream) {
    (void)in_sizes; (void)n_in; (void)out_size; (void)ws_size;

    const float* X    = (const float*)d_in[0];
    const float* pos  = (const float*)d_in[1];
    const int*   gmask= (const int*)  d_in[3];
    const float* Wq   = (const float*)d_in[4];
    const float* bq   = (const float*)d_in[5];
    const float* Wk   = (const float*)d_in[6];
    const float* bk   = (const float*)d_in[7];
    const float* Wv   = (const float*)d_in[8];
    const float* bv   = (const float*)d_in[9];
    float* out = (float*)d_out;

    char* ws = (char*)d_ws;
    u16*   wt   = (u16*)  (ws + OFF_WT);
    u16*   qrp  = (u16*)  (ws + OFF_QR);
    u16*   krp  = (u16*)  (ws + OFF_KR);
    u16*   vtp  = (u16*)  (ws + OFF_VT);
    u16*   App  = (u16*)  (ws + OFF_AP);

    k_prep <<<dim3(36),         dim3(256), 0, stream>>>(Wq, Wk, Wv, wt);
    k_qkv  <<<dim3(64, 9, 3),   dim3(256), 0, stream>>>(X, wt, bq, bk, bv, pos, qrp, krp, vtp);
    k_gemm1<<<dim3(1536),       dim3(256), 0, stream>>>(qrp, krp, App);
    k_gemm2<<<dim3(4, 9, 16),   dim3(256), 0, stream>>>(App, vtp, gmask, out);
}

// Round 13
// 169.588 us; speedup vs baseline: 1.0409x; 1.0086x over previous
//
#include <hip/hip_runtime.h>

// EuclideanFastAttention — MI355X (gfx950)
// A = (1/6) qr·kr^T per batch (256x256, K=6912, split by grid dir g=6),
// out = A·v.  R13 = R12 + XCD-aware 1-D decode on gemm2 (A-strips L2-resident
// per XCD; 9 dcb blocks per (rt,b) share one XCD's L2).

typedef unsigned short u16;
typedef __attribute__((ext_vector_type(8))) short short8;   // 8 x bf16 bits (MFMA frag)
typedef __attribute__((ext_vector_type(4))) float f32x4;    // MFMA acc

static constexpr int N_NODES = 4096;
static constexpr int NBATCH  = 16;
static constexpr int NB      = 256;
static constexpr int NDEG    = 9;
static constexpr int MD      = NDEG * 128;    // 1152
static constexpr int KTOT    = 6 * MD;        // 6912
static constexpr size_t ASLICE = (size_t)NBATCH * NB * NB;   // elems per g-slice of Apart

// ws layout (bytes), aliased along the kernel timeline
static constexpr size_t OFF_WT  = 0;                                  // 9*16384 bf16
static constexpr size_t OFF_QR  = OFF_WT  + (size_t)9*16384*2;        // [g][n][1152] 56.6MB
static constexpr size_t OFF_KR  = OFF_QR  + (size_t)N_NODES*KTOT*2;   // 56.6MB
static constexpr size_t OFF_VT  = OFF_KR  + (size_t)N_NODES*KTOT*2;   // [d][n] 9.4MB
static constexpr size_t OFF_AP  = OFF_VT  + (size_t)N_NODES*MD*2;     // 6*16*65536*2 = 12.6MB
// high-water = OFF_AP + 12.6MB = 135.6MB (proven in R6/R8/R10/R12)

__device__ inline u16 f2bf(float x) {
    union { float f; unsigned u; } v; v.f = x;
    unsigned r = v.u + 0x7fffu + ((v.u >> 16) & 1u);   // RNE
    return (u16)(r >> 16);
}
__device__ inline float bf2f(u16 h) {
    union { unsigned u; float f; } v; v.u = ((unsigned)h) << 16; return v.f;
}
// packed f32x2 -> bf16x2 (low = a).  HW RNE on gfx950 (1 VALU op vs ~8).
__device__ inline unsigned pk2bf(float a, float b) {
#if __has_builtin(__builtin_amdgcn_cvt_pk_bf16_f32)
    typedef __attribute__((ext_vector_type(2))) __bf16 bf2_t;
    union { bf2_t v; unsigned u; } cv;
    cv.v = __builtin_amdgcn_cvt_pk_bf16_f32(a, b);
    return cv.u;
#else
    return (unsigned)f2bf(a) | ((unsigned)f2bf(b) << 16);
#endif
}

// ---------------- kernel 1: W transpose + bf16 cast --------------------------
// wt[(mat*3+l)][j][f] = W[l][f][j];  grid 36 = 9 blk x 4 tiles
__global__ __launch_bounds__(256) void k_prep(const float* __restrict__ Wq,
                                              const float* __restrict__ Wk,
                                              const float* __restrict__ Wv,
                                              u16* __restrict__ wt) {
    int t = blockIdx.x, tid = threadIdx.x;
    int blk = t >> 2, tt = t & 3;
    int mat = blk / 3, l = blk % 3;
    const float* W = (mat == 0 ? Wq : (mat == 1 ? Wk : Wv)) + (size_t)l * 16384;
    int j0 = (tt >> 1) * 64, f0 = (tt & 1) * 64;
    __shared__ u16 tile[64 * 72];
    for (int e = tid; e < 1024; e += 256) {
        int r = e >> 4, c = e & 15;
        float4 wv = *(const float4*)(W + (size_t)(f0 + r) * 128 + j0 + c * 4);
        tile[(c * 4 + 0) * 72 + r] = f2bf(wv.x);
        tile[(c * 4 + 1) * 72 + r] = f2bf(wv.y);
        tile[(c * 4 + 2) * 72 + r] = f2bf(wv.z);
        tile[(c * 4 + 3) * 72 + r] = f2bf(wv.w);
    }
    __syncthreads();
    u16* dst = wt + (size_t)blk * 16384;
    for (int e = tid; e < 512; e += 256) {
        int j = e >> 3, c = e & 7;
        *(uint4*)(dst + (size_t)(j0 + j) * 128 + f0 + c * 8) = *(const uint4*)(tile + j * 72 + c * 8);
    }
}

// ---------------- kernel 2: dense(q/k/v) + bias + RoPE (inline trig) ---------
// grid (64 node-tiles, 9 m, 3 mats).  mat 2 writes vt[d][n] directly.
// qr/kr layout: [g][node][m*128+j]  (g-major for gemm1 streaming)
__global__ __launch_bounds__(256) void k_qkv(const float* __restrict__ X,
                                             const u16* __restrict__ wt,
                                             const float* __restrict__ bq,
                                             const float* __restrict__ bk,
                                             const float* __restrict__ bv,
                                             const float* __restrict__ pos,
                                             u16* __restrict__ qr,
                                             u16* __restrict__ kr,
                                             u16* __restrict__ vt) {
    const int nt = blockIdx.x, m = blockIdx.y, mat = blockIdx.z;
    const int n0 = nt * 64;
    const int deg = (m == 0) ? 0 : (m < 4 ? 1 : 2);
    const int tid = threadIdx.x;

    __shared__ u16 smem[26112];       // Xs(64x136) ++ Ws(128x136); reused as O0/O1/T
    __shared__ float posS[192];       // pos[n0..n0+63][3]
    u16* Xs = smem;
    u16* Ws = smem + 64 * 136;

    if (tid < 192) posS[tid] = pos[(size_t)n0 * 3 + tid];

    for (int e = tid; e < 2048; e += 256) {            // stage X (fp32->bf16, HW pk)
        int r = e >> 5, f4 = e & 31;
        float4 xv = *(const float4*)(X + (size_t)(n0 + r) * MD + m * 128 + f4 * 4);
        uint2 o = make_uint2(pk2bf(xv.x, xv.y), pk2bf(xv.z, xv.w));
        *(uint2*)(Xs + r * 136 + f4 * 4) = o;
    }
    {
        const uint4* wsrc = (const uint4*)(wt + (size_t)(mat * 3 + deg) * 16384);
        for (int e = tid; e < 2048; e += 256) {
            int j = e >> 4, f8 = e & 15;
            *(uint4*)(Ws + j * 136 + f8 * 8) = wsrc[j * 16 + f8];
        }
    }
    __syncthreads();

    const int w = tid >> 6, lane = tid & 63, quad = lane >> 4, lrow = lane & 15;
    f32x4 acc[8];
#pragma unroll
    for (int ct = 0; ct < 8; ct++) acc[ct] = (f32x4){0.f, 0.f, 0.f, 0.f};
#pragma unroll
    for (int ks = 0; ks < 4; ks++) {
        short8 a = *(const short8*)(Xs + (w * 16 + lrow) * 136 + ks * 32 + quad * 8);
#pragma unroll
        for (int ct = 0; ct < 8; ct++) {
            short8 bfr = *(const short8*)(Ws + (ct * 16 + lrow) * 136 + ks * 32 + quad * 8);
            acc[ct] = __builtin_amdgcn_mfma_f32_16x16x32_bf16(a, bfr, acc[ct], 0, 0, 0);
        }
    }

    const float* bias = (mat == 0) ? bq : ((mat == 1) ? bk : bv);
    float yv[8][4];
#pragma unroll
    for (int ct = 0; ct < 8; ct++) {
        float bj = (m == 0) ? bias[ct * 16 + lrow] : 0.0f;
#pragma unroll
        for (int r = 0; r < 4; r++) yv[ct][r] = acc[ct][r] + bj;
    }

    if (mat == 2) {                    // v: reg->LDS transpose T[j][nl], packed stores
        u16* T = Ws;                   // 128 x 66
        const int nlb = w * 16 + quad * 4;   // 4 consecutive nl per lane
        __syncthreads();
#pragma unroll
        for (int ct = 0; ct < 8; ct++) {
            int j = ct * 16 + lrow;
            *(unsigned*)(T + j * 66 + nlb)     = pk2bf(yv[ct][0], yv[ct][1]);
            *(unsigned*)(T + j * 66 + nlb + 2) = pk2bf(yv[ct][2], yv[ct][3]);
        }
        __syncthreads();
        for (int e = tid; e < 1024; e += 256) {
            int d = e >> 3, c = e & 7;
            *(uint4*)(vt + (size_t)(m * 128 + d) * N_NODES + n0 + c * 8) =
                *(const uint4*)(T + d * 66 + c * 8);
        }
        return;
    }

    float pv[8][4];                    // partner feature j^1 (same C row)
#pragma unroll
    for (int ct = 0; ct < 8; ct++)
#pragma unroll
        for (int r = 0; r < 4; r++) pv[ct][r] = __shfl_xor(yv[ct][r], 1);

    float pr[4][3];
#pragma unroll
    for (int r = 0; r < 4; r++) {
        int nl = w * 16 + quad * 4 + r;
#pragma unroll
        for (int gp = 0; gp < 3; gp++) pr[r][gp] = posS[nl * 3 + gp];
    }
    const float thq = (float)(lrow >> 1) * (8.0f / 630.0f);
    const float th8 = 8.0f * (8.0f / 630.0f);

    u16* O0 = Xs;                      // Xs dead after MFMA
    u16* O1 = Ws;
    u16* dst = (mat == 0) ? qr : kr;
    const bool even = !(lrow & 1);

    for (int gp = 0; gp < 3; gp++) {   // R10-proven scalar epilogue
        __syncthreads();
#pragma unroll
        for (int ct = 0; ct < 8; ct++) {
            float th = thq + (float)ct * th8;          // theta_i, i = ct*8 + (lrow>>1)
#pragma unroll
            for (int r = 0; r < 4; r++) {
                int nl = w * 16 + quad * 4 + r;
                float s, c;
                __sincosf(pr[r][gp] * th, &s, &c);
                float t1 = yv[ct][r] * c, t2 = pv[ct][r] * s;
                float r0, r1;
                if (even) { r0 = t1 - t2; r1 = t1 + t2; }
                else      { r0 = t1 + t2; r1 = t1 - t2; }
                O0[nl * 136 + ct * 16 + lrow] = f2bf(r0);
                O1[nl * 136 + ct * 16 + lrow] = f2bf(r1);
            }
        }
        __syncthreads();
        for (int e = tid; e < 1024; e += 256) {
            int nl = e >> 4, c = e & 15;
            size_t o0 = ((size_t)(gp * 2) * N_NODES + n0 + nl) * MD + m * 128 + c * 8;
            *(uint4*)(dst + o0)                      = *(const uint4*)(O0 + nl * 136 + c * 8);
            *(uint4*)(dst + o0 + (size_t)N_NODES*MD) = *(const uint4*)(O1 + nl * 136 + c * 8);
        }
    }
}

// ---------------- kernel 3: Apart[g] = qr_g · kr_g^T  (1-D XCD decode) -------
// 1536 blocks 1-D.  Under rr-8 XCD assignment, XCD c gets, per 64-block group
// (= 4 (b,g) pairs): one bg (c&3) and 8 tiles (2 q-strips x 4 k-strips)
// -> q 4x / k 2x reuse inside its L2.  [R9/R10: gemm1 out of top-5]
__global__ __launch_bounds__(256) void k_gemm1(const u16* __restrict__ qr,
                                               const u16* __restrict__ kr,
                                               u16* __restrict__ Apart) {
    int idx = blockIdx.x;              // 0..1535
    int grp = idx >> 6;                // 0..23
    int sub = idx & 63;
    int c   = sub & 7;                 // XCD id under round-robin-8
    int j   = sub >> 3;                // 0..7
    int bg  = grp * 4 + (c & 3);       // 0..95
    int g   = bg >> 4, b = bg & 15;
    int tr  = (c >> 2) * 2 + (j & 1);  // 0..3
    int tc  = j >> 1;                  // 0..3

    int qn0 = b * NB + tr * 64, kn0 = b * NB + tc * 64;
    const size_t gbase = (size_t)g * N_NODES;
    int tid = threadIdx.x;
    __shared__ u16 Qs[64 * 72];
    __shared__ u16 Ks[64 * 72];
    int w = tid >> 6, lane = tid & 63, quad = lane >> 4, lrow = lane & 15;

    f32x4 acc[4];
#pragma unroll
    for (int ct = 0; ct < 4; ct++) acc[ct] = (f32x4){0.f, 0.f, 0.f, 0.f};

    for (int kc = 0; kc < MD / 64; kc++) {     // 18
        int k0 = kc * 64;
#pragma unroll
        for (int e = tid; e < 512; e += 256) {
            int r = e >> 3, s = e & 7;
            *(uint4*)(Qs + r * 72 + s * 8) = *(const uint4*)(qr + (gbase + qn0 + r) * MD + k0 + s * 8);
            *(uint4*)(Ks + r * 72 + s * 8) = *(const uint4*)(kr + (gbase + kn0 + r) * MD + k0 + s * 8);
        }
        __syncthreads();
#pragma unroll
        for (int ks = 0; ks < 2; ks++) {
            short8 a = *(const short8*)(Qs + (w * 16 + lrow) * 72 + ks * 32 + quad * 8);
#pragma unroll
            for (int ct = 0; ct < 4; ct++) {
                short8 bfr = *(const short8*)(Ks + (ct * 16 + lrow) * 72 + ks * 32 + quad * 8);
                acc[ct] = __builtin_amdgcn_mfma_f32_16x16x32_bf16(a, bfr, acc[ct], 0, 0, 0);
            }
        }
        __syncthreads();
    }
    u16* dst = Apart + ((size_t)g * NBATCH + b) * (NB * NB);
#pragma unroll
    for (int ct = 0; ct < 4; ct++)
#pragma unroll
        for (int r = 0; r < 4; r++) {
            int rib = tr * 64 + w * 16 + quad * 4 + r;
            int cib = tc * 64 + ct * 16 + lrow;
            dst[(size_t)rib * NB + cib] = f2bf(acc[ct][r]);
        }
}

// ---------------- kernel 4: out = (1/6 sum_g Apart[g]) · v  (+mask) ----------
// 576 blocks 1-D, XCD-decoded: XCD c owns 8 (rt,b) pairs x all 9 dcb, so the
// 9 dcb blocks re-read their A-strips (6 slices) from c's L2, not L3.
// Working set/XCD: 8 x 196KB A + vt for 2 b's ~ 2.8MB < 4MB L2.
__global__ __launch_bounds__(256) void k_gemm2(const u16* __restrict__ Ap,
                                               const u16* __restrict__ vt,
                                               const int* __restrict__ gmask,
                                               float* __restrict__ out) {
    int idx = blockIdx.x;              // 0..575
    int c   = idx & 7;                 // XCD id under round-robin-8
    int u   = idx >> 3;                // 0..71
    int pr9 = u / 9;                   // 0..7
    int dcb = u - pr9 * 9;             // 0..8
    int pair = pr9 * 8 + c;            // 0..63
    int rt  = pair >> 4, b = pair & 15;
    int d0 = dcb * 128;
    int tid = threadIdx.x;
    __shared__ u16 As[64 * 72];
    __shared__ u16 Vs[128 * 72];
    int w = tid >> 6, lane = tid & 63, quad = lane >> 4, lrow = lane & 15;

    f32x4 acc[8];
#pragma unroll
    for (int ct = 0; ct < 8; ct++) acc[ct] = (f32x4){0.f, 0.f, 0.f, 0.f};

    const float sc6 = 1.0f / 6.0f;
    for (int kc = 0; kc < 4; kc++) {
        int k0 = kc * 64;
#pragma unroll
        for (int e = tid; e < 512; e += 256) {     // A: sum 6 slices, scale, pack (HW pk)
            int r = e >> 3, c8 = e & 7;
            size_t off = (size_t)b * (NB * NB) + (size_t)(rt * 64 + r) * NB + k0 + c8 * 8;
            float sacc[8];
#pragma unroll
            for (int i = 0; i < 8; i++) sacc[i] = 0.f;
#pragma unroll
            for (int s = 0; s < 6; s++) {
                uint4 v = *(const uint4*)(Ap + (size_t)s * ASLICE + off);
                const unsigned* uu = (const unsigned*)&v;
#pragma unroll
                for (int h = 0; h < 4; h++) {
                    sacc[h * 2]     += bf2f((u16)(uu[h] & 0xffff));
                    sacc[h * 2 + 1] += bf2f((u16)(uu[h] >> 16));
                }
            }
            unsigned o32[4];
#pragma unroll
            for (int i = 0; i < 4; i++) o32[i] = pk2bf(sacc[i * 2] * sc6, sacc[i * 2 + 1] * sc6);
            *(uint4*)(As + r * 72 + c8 * 8) = *(const uint4*)o32;
        }
#pragma unroll
        for (int e = tid; e < 1024; e += 256) {
            int rr = e >> 3, sc2 = e & 7;
            *(uint4*)(Vs + rr * 72 + sc2 * 8) =
                *(const uint4*)(vt + (size_t)(d0 + rr) * N_NODES + b * NB + k0 + sc2 * 8);
        }
        __syncthreads();
#pragma unroll
        for (int ks = 0; ks < 2; ks++) {
            short8 a = *(const short8*)(As + (w * 16 + lrow) * 72 + ks * 32 + quad * 8);
#pragma unroll
            for (int ct = 0; ct < 8; ct++) {
                short8 bfr = *(const short8*)(Vs + (ct * 16 + lrow) * 72 + ks * 32 + quad * 8);
                acc[ct] = __builtin_amdgcn_mfma_f32_16x16x32_bf16(a, bfr, acc[ct], 0, 0, 0);
            }
        }
        __syncthreads();
    }
    int mv = gmask[b];
#pragma unroll
    for (int ct = 0; ct < 8; ct++)
#pragma unroll
        for (int r = 0; r < 4; r++) {
            int node = b * NB + rt * 64 + w * 16 + quad * 4 + r;
            int d = d0 + ct * 16 + lrow;
            out[(size_t)node * MD + d] = mv ? acc[ct][r] : 0.0f;
        }
}

// ---------------- launch -----------------------------------------------------
extern "C" void kernel_launch(void* const* d_in, const int* in_sizes, int n_in,
                              void* d_out, int out_size, void* d_ws, size_t ws_size,
                              hipStream_t stream) {
    (void)in_sizes; (void)n_in; (void)out_size; (void)ws_size;

    const float* X    = (const float*)d_in[0];
    const float* pos  = (const float*)d_in[1];
    const int*   gmask= (const int*)  d_in[3];
    const float* Wq   = (const float*)d_in[4];
    const float* bq   = (const float*)d_in[5];
    const float* Wk   = (const float*)d_in[6];
    const float* bk   = (const float*)d_in[7];
    const float* Wv   = (const float*)d_in[8];
    const float* bv   = (const float*)d_in[9];
    float* out = (float*)d_out;

    char* ws = (char*)d_ws;
    u16*   wt   = (u16*)  (ws + OFF_WT);
    u16*   qrp  = (u16*)  (ws + OFF_QR);
    u16*   krp  = (u16*)  (ws + OFF_KR);
    u16*   vtp  = (u16*)  (ws + OFF_VT);
    u16*   App  = (u16*)  (ws + OFF_AP);

    k_prep <<<dim3(36),         dim3(256), 0, stream>>>(Wq, Wk, Wv, wt);
    k_qkv  <<<dim3(64, 9, 3),   dim3(256), 0, stream>>>(X, wt, bq, bk, bv, pos, qrp, krp, vtp);
    k_gemm1<<<dim3(1536),       dim3(256), 0, stream>>>(qrp, krp, App);
    k_gemm2<<<dim3(576),        dim3(256), 0, stream>>>(App, vtp, gmask, out);
}